// Round 11
// baseline (113.892 us; speedup 1.0000x reference)
//
#include <hip/hip_runtime.h>

#define T_SEQ 2048
#define CDIM 1024
#define NHEAD 16
#define HDIM 64
#define BATCH 2
#define EPSV 1e-5f
#define SCALE 0.125f
#define LOG2E 1.44269504088896f
#define SMAX 16.0f  // fixed softmax max: scores bounded by 64*SCALE*LOG2E=11.54 < 16

typedef __attribute__((ext_vector_type(8))) short bf16x8;
typedef __attribute__((ext_vector_type(4))) float f32x4;

__device__ __forceinline__ float b2f(short s) {
  unsigned u = ((unsigned)(unsigned short)s) << 16;
  return __builtin_bit_cast(float, u);
}
__device__ __forceinline__ short f2b(float f) {
  unsigned u = __builtin_bit_cast(unsigned, f);
  unsigned r = (u + 0x7fffu + ((u >> 16) & 1u)) >> 16;
  return (short)r;
}
__device__ __forceinline__ unsigned cvt_pk_bf16(float a, float b) {
  unsigned r;
  asm("v_cvt_pk_bf16_f32 %0, %1, %2" : "=v"(r) : "v"(a), "v"(b));
  return r;
}

__device__ __forceinline__ void gld16(const void* g, void* l) {
  __builtin_amdgcn_global_load_lds((const __attribute__((address_space(1))) unsigned*)g,
                                   (__attribute__((address_space(3))) unsigned*)l, 16, 0, 0);
}

// GEMM tile swizzle: rows are 64 B (32 shorts) -> bank period = 2 rows. 16-lane
// fragment reads hit 16 consecutive rows; swz must mix row bits >=1 so the 8
// same-parity rows spread 2-per-4-bank-slot (2-way = free). (row&3) alone left
// lanes {c,c+4,c+8,c+12} on one slot = 4-way conflict.
__device__ __forceinline__ int gswz(int row) { return ((row >> 1) ^ (row >> 3)) & 3; }

// Stage rows of 128 B global->LDS, linear LDS dest, pre-swizzled global source:
// byte-in-row ^= (row&7)<<4.  stage_sw: 2 KB per wave (wave w -> rows 16w..16w+15).
__device__ __forceinline__ void stage_sw(short* lds, const char* gbase, int gstride,
                                         int w, int l) {
#pragma unroll
  for (int i = 0; i < 2; ++i) {
    int chunk = w * 2048 + i * 1024 + l * 16;
    int row = chunk >> 7;
    int bir = chunk & 127;
    const char* src = gbase + (size_t)row * gstride + (bir ^ ((row & 7) << 4));
    gld16(src, (char*)lds + chunk);
  }
}
// 1 KB per wave (8 waves cover a 64-row tile; wave w -> rows 8w..8w+7).
__device__ __forceinline__ void stage_sw8(short* lds, const char* gbase, int gstride,
                                          int w, int l) {
  int chunk = w * 1024 + l * 16;
  int row = chunk >> 7;
  int bir = chunk & 127;
  const char* src = gbase + (size_t)row * gstride + (bir ^ ((row & 7) << 4));
  gld16(src, (char*)lds + chunk);
}

// ---------------- prep: x fp32->bf16 (blocks 0..2047) + W transpose (2048..3071) ----
__global__ __launch_bounds__(256) void prep(const float* __restrict__ x,
                                            const float* __restrict__ Wq,
                                            const float* __restrict__ Wk,
                                            const float* __restrict__ Wv,
                                            const float* __restrict__ Wo,
                                            short* __restrict__ xb,
                                            short* __restrict__ WT) {
  __shared__ float tile[64][65];
  const int bid = blockIdx.x;
  if (bid < 2048) {
    size_t i = ((size_t)bid * 256 + threadIdx.x) * 8;
    float4 a = *(const float4*)&x[i];
    float4 b = *(const float4*)&x[i + 4];
    short4 lo, hi;
    lo.x = f2b(a.x); lo.y = f2b(a.y); lo.z = f2b(a.z); lo.w = f2b(a.w);
    hi.x = f2b(b.x); hi.y = f2b(b.y); hi.z = f2b(b.z); hi.w = f2b(b.w);
    *(short4*)&xb[i] = lo;
    *(short4*)&xb[i + 4] = hi;
    return;
  }
  const int t = bid - 2048;
  const int z = t >> 8, rem = t & 255;
  const float* W = (z == 0) ? Wq : (z == 1) ? Wk : (z == 2) ? Wv : Wo;
  const int r0 = (rem >> 4) * 64, c0 = (rem & 15) * 64;
  const int tr = threadIdx.x >> 4, tc4 = (threadIdx.x & 15) * 4;
#pragma unroll
  for (int i = 0; i < 4; ++i) {
    float4 v = *(const float4*)&W[(size_t)(r0 + tr + i * 16) * 1024 + c0 + tc4];
    tile[tr + i * 16][tc4 + 0] = v.x;
    tile[tr + i * 16][tc4 + 1] = v.y;
    tile[tr + i * 16][tc4 + 2] = v.z;
    tile[tr + i * 16][tc4 + 3] = v.w;
  }
  __syncthreads();
#pragma unroll
  for (int i = 0; i < 4; ++i) {
    int n = tr + i * 16;
    short4 o;
    o.x = f2b(tile[tc4 + 0][n]);
    o.y = f2b(tile[tc4 + 1][n]);
    o.z = f2b(tile[tc4 + 2][n]);
    o.w = f2b(tile[tc4 + 3][n]);
    *(short4*)&WT[((size_t)(z * 1024) + c0 + n) * 1024 + r0 + tc4] = o;
  }
}

// ---------------- bf16 MFMA GEMM: C[M,N] = A[M,K] @ Bt[N,K]^T ----------------
// BM=128, BN templated, BK=32, 256 threads (4 waves 2x2). Triple-buffered LDS,
// depth-2 prefetch, counted vmcnt (never 0 mid-loop) + raw s_barrier.
// LDS tiles use gswz (2-way-max bank swizzle), pre-swizzled global source.
// NORM: fused per-head RMSNorm on Q (cols<1024, *SCALE*LOG2E) / K (1024..2047).
template <int BN, bool F32OUT, bool NORM>
__global__ __launch_bounds__(256) void gemm_bf16(const short* __restrict__ A,
                                                 const short* __restrict__ Bt,
                                                 void* __restrict__ Cv,
                                                 const float* __restrict__ qw,
                                                 const float* __restrict__ kw,
                                                 int M, int N, int K, int nbx) {
  constexpr int NFR = BN / 32;
  constexpr int BITERS = BN / 64;
  __shared__ __attribute__((aligned(16))) short As[3][4096];
  __shared__ __attribute__((aligned(16))) short Bs[3][BN * 32];
  const int tid = threadIdx.x;
  const int w = tid >> 6, l = tid & 63;
  const int g = l >> 4, c = l & 15;
  const int wm = w >> 1, wn = w & 1;
  // XCD-bijective swizzle (gridDim.x % 8 == 0)
  const int cpx = gridDim.x >> 3;
  const int wg = (blockIdx.x & 7) * cpx + (blockIdx.x >> 3);
  const int bx = wg % nbx, by = wg / nbx;
  const int m0 = by * 128, n0 = bx * BN;
  const char* Ab = (const char*)A;
  const char* Bb = (const char*)Bt;

  auto stage = [&](int k0, int buf) {
#pragma unroll
    for (int i = 0; i < 2; ++i) {
      int ci = w * 128 + i * 64 + l;
      int row = ci >> 2, c4 = ci & 3;
      gld16(Ab + ((size_t)(m0 + row) * K + k0) * 2 + ((c4 ^ gswz(row)) << 4),
            (char*)As[buf] + (w * 2048 + i * 1024));
    }
#pragma unroll
    for (int i = 0; i < BITERS; ++i) {
      int ci = w * (64 * BITERS) + i * 64 + l;
      int row = ci >> 2, c4 = ci & 3;
      gld16(Bb + ((size_t)(n0 + row) * K + k0) * 2 + ((c4 ^ gswz(row)) << 4),
            (char*)Bs[buf] + (w * (1024 * BITERS) + i * 1024));
    }
  };

  f32x4 acc[4][NFR];
#pragma unroll
  for (int mt = 0; mt < 4; ++mt)
#pragma unroll
    for (int nt = 0; nt < NFR; ++nt) {
      f32x4 z = {0.f, 0.f, 0.f, 0.f};
      acc[mt][nt] = z;
    }

  const int NT = K >> 5;
  stage(0, 0);
  stage(32, 1);
  if constexpr (BITERS == 2) asm volatile("s_waitcnt vmcnt(4)" ::: "memory");
  else                       asm volatile("s_waitcnt vmcnt(3)" ::: "memory");
  __builtin_amdgcn_s_barrier();
  __builtin_amdgcn_sched_barrier(0);

  int cbuf = 0;
  for (int t = 0; t < NT; ++t) {
    int tgt = cbuf + 2; if (tgt >= 3) tgt -= 3;
    if (t + 2 < NT) stage((t + 2) << 5, tgt);
    bf16x8 a[4], bf[NFR];
#pragma unroll
    for (int mt = 0; mt < 4; ++mt) {
      const int row = wm * 64 + mt * 16 + c;
      a[mt] = *(const bf16x8*)&As[cbuf][row * 32 + ((g ^ gswz(row)) << 3)];
    }
#pragma unroll
    for (int nt = 0; nt < NFR; ++nt) {
      const int row = wn * (BN / 2) + nt * 16 + c;
      bf[nt] = *(const bf16x8*)&Bs[cbuf][row * 32 + ((g ^ gswz(row)) << 3)];
    }
    __builtin_amdgcn_s_setprio(1);
#pragma unroll
    for (int mt = 0; mt < 4; ++mt)
#pragma unroll
      for (int nt = 0; nt < NFR; ++nt)
        acc[mt][nt] = __builtin_amdgcn_mfma_f32_16x16x32_bf16(a[mt], bf[nt], acc[mt][nt], 0, 0, 0);
    __builtin_amdgcn_s_setprio(0);
    if (t + 1 < NT) {
      if (t + 2 < NT) {
        if constexpr (BITERS == 2) asm volatile("s_waitcnt vmcnt(4)" ::: "memory");
        else                       asm volatile("s_waitcnt vmcnt(3)" ::: "memory");
      } else {
        asm volatile("s_waitcnt vmcnt(0)" ::: "memory");
      }
      __builtin_amdgcn_s_barrier();
      __builtin_amdgcn_sched_barrier(0);
    }
    cbuf = cbuf + 1; if (cbuf >= 3) cbuf -= 3;
  }

  if constexpr (NORM) {
    if (n0 < 2048) {
      const float* wgt = (n0 < 1024) ? qw : kw;
      const float scl = (n0 < 1024) ? SCALE * LOG2E : 1.f;
      float w4[NFR];
#pragma unroll
      for (int nt = 0; nt < NFR; ++nt) w4[nt] = wgt[nt * 16 + c] * scl;
#pragma unroll
      for (int mt = 0; mt < 4; ++mt)
#pragma unroll
        for (int r = 0; r < 4; ++r) {
          float s = 0.f;
#pragma unroll
          for (int nt = 0; nt < NFR; ++nt) s += acc[mt][nt][r] * acc[mt][nt][r];
          s += __shfl_xor(s, 1);
          s += __shfl_xor(s, 2);
          s += __shfl_xor(s, 4);
          s += __shfl_xor(s, 8);
          const float rstd = rsqrtf(s * (1.0f / 64.0f) + EPSV);
#pragma unroll
          for (int nt = 0; nt < NFR; ++nt) acc[mt][nt][r] *= rstd * w4[nt];
        }
    }
  }

  if constexpr (F32OUT) {
    float* C = (float*)Cv;
#pragma unroll
    for (int mt = 0; mt < 4; ++mt)
#pragma unroll
      for (int nt = 0; nt < NFR; ++nt)
#pragma unroll
        for (int r = 0; r < 4; ++r)
          C[(size_t)(m0 + wm * 64 + mt * 16 + 4 * g + r) * N + n0 + wn * (BN / 2) + nt * 16 + c] =
              acc[mt][nt][r];
  } else {
    short* C = (short*)Cv;
#pragma unroll
    for (int mt = 0; mt < 4; ++mt)
#pragma unroll
      for (int nt = 0; nt < NFR; ++nt)
#pragma unroll
        for (int r = 0; r < 4; ++r)
          C[(size_t)(m0 + wm * 64 + mt * 16 + 4 * g + r) * N + n0 + wn * (BN / 2) + nt * 16 + c] =
              f2b(acc[mt][nt][r]);
  }
}

// ---------------- V transpose via LDS (coalesced both sides) ----------------
__global__ __launch_bounds__(256) void vt_kernel(const short* __restrict__ QKV,
                                                 short* __restrict__ VT) {
  __shared__ short tile[64][66];
  const int t0 = blockIdx.x * 64;
  const int h = blockIdx.y, b = blockIdx.z;
  const int tid = threadIdx.x;
  const int r = tid >> 3, c8 = (tid & 7) * 8;
#pragma unroll
  for (int p = 0; p < 2; ++p) {
    int row = r + p * 32;
    bf16x8 v = *(const bf16x8*)&QKV[(size_t)(b * T_SEQ + t0 + row) * 3072 + 2048 + h * 64 + c8];
#pragma unroll
    for (int j = 0; j < 8; ++j) tile[row][c8 + j] = v[j];
  }
  __syncthreads();
#pragma unroll
  for (int p = 0; p < 2; ++p) {
    int d = r + p * 32;
    short o[8];
#pragma unroll
    for (int j = 0; j < 8; ++j) o[j] = tile[c8 + j][d];
    *(bf16x8*)&VT[((size_t)(b * NHEAD + h) * 64 + d) * T_SEQ + t0 + c8] = *(bf16x8*)o;
  }
}

// ---------------- MFMA flash attention: 8-wave QBLK=128, counted-vmcnt ------
// 512 blocks (2/CU grid-limited, LDS 64 KB), block = (b,h,128 q rows). Pair map:
// CU's two residents get Q16 and 15-Q16 (34 k-iters total, same bh -> L2 reuse).
// Triple-buffered K/V, depth-2 prefetch, per-iter vmcnt(2) + one raw s_barrier.
// Fixed-max softmax: QK acc init = -SMAX, P = exp2(s); lsum via ones-MFMA.
__global__ __launch_bounds__(512, 4) void attn_fwd(const short* __restrict__ QKV,
                                                   const short* __restrict__ VT,
                                                   const float* __restrict__ gate,
                                                   short* __restrict__ Ob) {
  __shared__ __attribute__((aligned(16))) short pool[32768];  // 64 KB
  // shorts: [0,8192) Q 128x64 (dead after qf -> 8x 1K-short P slices);
  // [8192+buf*4096) K bufs (buf<3); [20480+buf*4096) V bufs.

  const int bid = blockIdx.x;
  const int xcd = bid & 7, s = bid >> 3;  // s 0..63
  const int t8 = (s >> 2) & 7;
  const int Q16 = (s < 32) ? 15 - t8 : t8;  // pair-balanced: s & s+32 sum to 34 iters
  const int bh = xcd * 4 + (s & 3);
  const int h = bh & 15, b = bh >> 4;
  const int q0 = Q16 * 128;
  const int nkt = 2 * Q16 + 2;
  const int tid = threadIdx.x;
  const int w = tid >> 6, l = tid & 63;
  const int g = l >> 4, c = l & 15;

  const char* qkb = (const char*)QKV;
  const char* kbase = qkb + ((size_t)(b * T_SEQ) * 3072 + 1024 + h * 64) * 2;
  const char* vtb = (const char*)VT + ((size_t)(b * NHEAD + h) * 64) * T_SEQ * 2;
  const float gh = gate[h];

  // prologue: Q (2 loads/lane), tiles 0 and 1 (2 loads/lane each; nkt >= 2 always)
  stage_sw(pool, qkb + ((size_t)(b * T_SEQ + q0) * 3072 + h * 64) * 2, 3072 * 2, w, l);
  stage_sw8(pool + 8192, kbase, 3072 * 2, w, l);
  stage_sw8(pool + 20480, vtb, T_SEQ * 2, w, l);
  stage_sw8(pool + 8192 + 4096, kbase + (size_t)64 * 3072 * 2, 3072 * 2, w, l);
  stage_sw8(pool + 20480 + 4096, vtb + (size_t)64 * 2, T_SEQ * 2, w, l);
  asm volatile("s_waitcnt vmcnt(4)" ::: "memory");  // Q landed; tiles 0,1 in flight
  __builtin_amdgcn_sched_barrier(0);

  // qf: wave w staged exactly rows 16w..16w+15 -> own-wave data, no barrier
  bf16x8 qf[2];
  {
    const int row = w * 16 + c;  // 0..127
#pragma unroll
    for (int ks = 0; ks < 2; ++ks)
      qf[ks] = *(const bf16x8*)&pool[row * 64 + ((ks * 32 + g * 8) ^ ((row & 7) << 3))];
  }
  short* ps = pool + (w << 10);  // per-wave P slice aliases this wave's Q rows

  bf16x8 onesf;
#pragma unroll
  for (int j = 0; j < 8; ++j) onesf[j] = (short)0x3F80;  // bf16 1.0

  f32x4 oacc[4];
#pragma unroll
  for (int dt = 0; dt < 4; ++dt) {
    f32x4 z = {0.f, 0.f, 0.f, 0.f};
    oacc[dt] = z;
  }
  f32x4 oacc4 = {0.f, 0.f, 0.f, 0.f};  // lsum accumulator (ones-MFMA)
  int cur = 0;

  for (int kt = 0; kt < nkt; ++kt) {
    // tile kt landed (leave tile kt+1's 2 loads in flight); sync; then prefetch kt+2
    if (kt + 1 < nkt) asm volatile("s_waitcnt vmcnt(2)" ::: "memory");
    else              asm volatile("s_waitcnt vmcnt(0)" ::: "memory");
    __builtin_amdgcn_s_barrier();
    __builtin_amdgcn_sched_barrier(0);
    if (kt + 2 < nkt) {
      int tgt = cur + 2; if (tgt >= 3) tgt -= 3;
      stage_sw8(pool + 8192 + (tgt << 12), kbase + (size_t)(kt + 2) * 64 * 3072 * 2, 3072 * 2, w, l);
      stage_sw8(pool + 20480 + (tgt << 12), vtb + (size_t)(kt + 2) * 64 * 2, T_SEQ * 2, w, l);
    }
    const short* Ks = pool + 8192 + (cur << 12);
    const short* Vs = pool + 20480 + (cur << 12);
    const int dq = q0 + w * 16 - kt * 64;  // wave-relative diagonal offset
    if (dq > -16) {  // wave has at least one unmasked (q,k) in this tile
      f32x4 sacc[4];
#pragma unroll
      for (int mt = 0; mt < 4; ++mt) {
        f32x4 z = {-SMAX, -SMAX, -SMAX, -SMAX};  // fixed-max subtract, free
        sacc[mt] = z;
      }
      __builtin_amdgcn_s_setprio(1);
#pragma unroll
      for (int mt = 0; mt < 4; ++mt) {
        const int row = mt * 16 + c;
#pragma unroll
        for (int ks = 0; ks < 2; ++ks) {
          bf16x8 kf = *(const bf16x8*)&Ks[row * 64 + ((ks * 32 + g * 8) ^ ((row & 7) << 3))];
          sacc[mt] = __builtin_amdgcn_mfma_f32_16x16x32_bf16(kf, qf[ks], sacc[mt], 0, 0, 0);
        }
      }
      __builtin_amdgcn_s_setprio(0);
      // hoist V fragment reads (overlap with softmax VALU)
      bf16x8 vf[4][2];
#pragma unroll
      for (int dt = 0; dt < 4; ++dt) {
        const int row = dt * 16 + c;
#pragma unroll
        for (int ks = 0; ks < 2; ++ks)
          vf[dt][ks] = *(const bf16x8*)&Vs[row * 64 + ((ks * 32 + g * 8) ^ ((row & 7) << 3))];
      }
      if (dq < 63) {  // diagonal tile for this wave: mask k > q
#pragma unroll
        for (int mt = 0; mt < 4; ++mt)
#pragma unroll
          for (int r = 0; r < 4; ++r)
            if (mt * 16 + 4 * g + r > dq + c) sacc[mt][r] = -1e30f;
      }
      // P = exp2(s) straight off MFMA output; pack and stash in ps
#pragma unroll
      for (int mt = 0; mt < 4; ++mt) {
        float p0 = exp2f(sacc[mt][0]);
        float p1 = exp2f(sacc[mt][1]);
        float p2 = exp2f(sacc[mt][2]);
        float p3 = exp2f(sacc[mt][3]);
        uint2 pk;
        pk.x = cvt_pk_bf16(p0, p1);
        pk.y = cvt_pk_bf16(p2, p3);
        *(uint2*)&ps[(c << 6) + ((mt * 16 + 4 * g) ^ ((c & 7) << 3))] = pk;
      }
      bf16x8 pb[2];
#pragma unroll
      for (int ks = 0; ks < 2; ++ks)
        pb[ks] = *(const bf16x8*)&ps[(c << 6) + ((ks * 32 + g * 8) ^ ((c & 7) << 3))];
      __builtin_amdgcn_s_setprio(1);
#pragma unroll
      for (int dt = 0; dt < 4; ++dt)
#pragma unroll
        for (int ks = 0; ks < 2; ++ks)
          oacc[dt] = __builtin_amdgcn_mfma_f32_16x16x32_bf16(vf[dt][ks], pb[ks], oacc[dt], 0, 0, 0);
      // lsum: row-sum of P via ones A-operand (matrix pipe, replaces VALU adds)
      oacc4 = __builtin_amdgcn_mfma_f32_16x16x32_bf16(onesf, pb[0], oacc4, 0, 0, 0);
      oacc4 = __builtin_amdgcn_mfma_f32_16x16x32_bf16(onesf, pb[1], oacc4, 0, 0, 0);
      __builtin_amdgcn_s_setprio(0);
    }
    cur = (cur + 1 == 3) ? 0 : cur + 1;
  }
  // epilogue: lsum from ones-MFMA (all 4 regs identical), gate/l, value residual
  const float gl = gh / oacc4[0];
  const int qrow = q0 + w * 16 + c;
  const short* Vr = QKV + (size_t)(b * T_SEQ + qrow) * 3072 + 2048 + h * 64;
  short* Oro = Ob + (size_t)(b * T_SEQ + qrow) * 1024 + h * 64;
#pragma unroll
  for (int dt = 0; dt < 4; ++dt) {
    const int d0 = dt * 16 + 4 * g;
    short4 vres = *(const short4*)&Vr[d0];
    short4 o;
    o.x = f2b(oacc[dt][0] * gl + b2f(vres.x));
    o.y = f2b(oacc[dt][1] * gl + b2f(vres.y));
    o.z = f2b(oacc[dt][2] * gl + b2f(vres.z));
    o.w = f2b(oacc[dt][3] * gl + b2f(vres.w));
    *(short4*)&Oro[d0] = o;
  }
}

extern "C" void kernel_launch(void* const* d_in, const int* in_sizes, int n_in,
                              void* d_out, int out_size, void* d_ws, size_t ws_size,
                              hipStream_t stream) {
  const float* x  = (const float*)d_in[0];
  const float* Wq = (const float*)d_in[2];
  const float* Wk = (const float*)d_in[3];
  const float* Wv = (const float*)d_in[4];
  const float* Wo = (const float*)d_in[5];
  const float* qw = (const float*)d_in[6];
  const float* kw = (const float*)d_in[7];
  const float* gate = (const float*)d_in[8];
  float* out = (float*)d_out;

  char* ws = (char*)d_ws;
  short* xb  = (short*)ws;                        // 8 MB
  short* WT  = (short*)(ws + ((size_t)8 << 20));  // 8 MB  [4096][1024]: WqT,WkT,WvT,WoT
  short* QKV = (short*)(ws + ((size_t)16 << 20)); // 24 MB [4096][3072]
  short* VTb = (short*)(ws + ((size_t)40 << 20)); // 8 MB  [b,h,64,2048]
  short* Obf = (short*)(ws + ((size_t)48 << 20)); // 8 MB  [4096][1024]

  const int M = BATCH * T_SEQ;  // 4096

  prep<<<3072, 256, 0, stream>>>(x, Wq, Wk, Wv, Wo, xb, WT);
  gemm_bf16<128, false, true><<<768, 256, 0, stream>>>(xb, WT, QKV, qw, kw, M, 3072, CDIM, 24);
  vt_kernel<<<dim3(32, 16, 2), 256, 0, stream>>>(QKV, VTb);
  attn_fwd<<<512, 512, 0, stream>>>(QKV, VTb, gate, Obf);
  gemm_bf16<64, true, false><<<512, 256, 0, stream>>>(Obf, WT + (size_t)3072 * 1024, out,
                                                      nullptr, nullptr, M, CDIM, CDIM, 16);
}

// Round 12
// 111.096 us; speedup vs baseline: 1.0252x; 1.0252x over previous
//
#include <hip/hip_runtime.h>

#define T_SEQ 2048
#define CDIM 1024
#define NHEAD 16
#define HDIM 64
#define BATCH 2
#define EPSV 1e-5f
#define SCALE 0.125f
#define LOG2E 1.44269504088896f
#define SMAX 16.0f  // fixed softmax max: scores bounded by 64*SCALE*LOG2E=11.54 < 16

typedef __attribute__((ext_vector_type(8))) short bf16x8;
typedef __attribute__((ext_vector_type(4))) float f32x4;

__device__ __forceinline__ float b2f(short s) {
  unsigned u = ((unsigned)(unsigned short)s) << 16;
  return __builtin_bit_cast(float, u);
}
__device__ __forceinline__ short f2b(float f) {
  unsigned u = __builtin_bit_cast(unsigned, f);
  unsigned r = (u + 0x7fffu + ((u >> 16) & 1u)) >> 16;
  return (short)r;
}
__device__ __forceinline__ unsigned cvt_pk_bf16(float a, float b) {
  unsigned r;
  asm("v_cvt_pk_bf16_f32 %0, %1, %2" : "=v"(r) : "v"(a), "v"(b));
  return r;
}

__device__ __forceinline__ void gld16(const void* g, void* l) {
  __builtin_amdgcn_global_load_lds((const __attribute__((address_space(1))) unsigned*)g,
                                   (__attribute__((address_space(3))) unsigned*)l, 16, 0, 0);
}

// GEMM tile swizzle (R11; kept — conflict counter proved insensitive either way).
__device__ __forceinline__ int gswz(int row) { return ((row >> 1) ^ (row >> 3)) & 3; }

// Stage rows of 128 B global->LDS, linear LDS dest, pre-swizzled global source:
// byte-in-row ^= (row&7)<<4.  stage_sw: 2 KB per wave (wave w -> rows 16w..16w+15).
__device__ __forceinline__ void stage_sw(short* lds, const char* gbase, int gstride,
                                         int w, int l) {
#pragma unroll
  for (int i = 0; i < 2; ++i) {
    int chunk = w * 2048 + i * 1024 + l * 16;
    int row = chunk >> 7;
    int bir = chunk & 127;
    const char* src = gbase + (size_t)row * gstride + (bir ^ ((row & 7) << 4));
    gld16(src, (char*)lds + chunk);
  }
}
// 1 KB per wave (8 waves cover a 64-row tile; wave w -> rows 8w..8w+7).
__device__ __forceinline__ void stage_sw8(short* lds, const char* gbase, int gstride,
                                          int w, int l) {
  int chunk = w * 1024 + l * 16;
  int row = chunk >> 7;
  int bir = chunk & 127;
  const char* src = gbase + (size_t)row * gstride + (bir ^ ((row & 7) << 4));
  gld16(src, (char*)lds + chunk);
}

// ---------------- prep: x fp32->bf16 (blocks 0..2047) + W transpose (2048..3071) ----
__global__ __launch_bounds__(256) void prep(const float* __restrict__ x,
                                            const float* __restrict__ Wq,
                                            const float* __restrict__ Wk,
                                            const float* __restrict__ Wv,
                                            const float* __restrict__ Wo,
                                            short* __restrict__ xb,
                                            short* __restrict__ WT) {
  __shared__ float tile[64][65];
  const int bid = blockIdx.x;
  if (bid < 2048) {
    size_t i = ((size_t)bid * 256 + threadIdx.x) * 8;
    float4 a = *(const float4*)&x[i];
    float4 b = *(const float4*)&x[i + 4];
    short4 lo, hi;
    lo.x = f2b(a.x); lo.y = f2b(a.y); lo.z = f2b(a.z); lo.w = f2b(a.w);
    hi.x = f2b(b.x); hi.y = f2b(b.y); hi.z = f2b(b.z); hi.w = f2b(b.w);
    *(short4*)&xb[i] = lo;
    *(short4*)&xb[i + 4] = hi;
    return;
  }
  const int t = bid - 2048;
  const int z = t >> 8, rem = t & 255;
  const float* W = (z == 0) ? Wq : (z == 1) ? Wk : (z == 2) ? Wv : Wo;
  const int r0 = (rem >> 4) * 64, c0 = (rem & 15) * 64;
  const int tr = threadIdx.x >> 4, tc4 = (threadIdx.x & 15) * 4;
#pragma unroll
  for (int i = 0; i < 4; ++i) {
    float4 v = *(const float4*)&W[(size_t)(r0 + tr + i * 16) * 1024 + c0 + tc4];
    tile[tr + i * 16][tc4 + 0] = v.x;
    tile[tr + i * 16][tc4 + 1] = v.y;
    tile[tr + i * 16][tc4 + 2] = v.z;
    tile[tr + i * 16][tc4 + 3] = v.w;
  }
  __syncthreads();
#pragma unroll
  for (int i = 0; i < 4; ++i) {
    int n = tr + i * 16;
    short4 o;
    o.x = f2b(tile[tc4 + 0][n]);
    o.y = f2b(tile[tc4 + 1][n]);
    o.z = f2b(tile[tc4 + 2][n]);
    o.w = f2b(tile[tc4 + 3][n]);
    *(short4*)&WT[((size_t)(z * 1024) + c0 + n) * 1024 + r0 + tc4] = o;
  }
}

// ---------------- bf16 MFMA GEMM: C[M,N] = A[M,K] @ Bt[N,K]^T ----------------
// BM=128, BN templated, BK=32, 256 threads (4 waves 2x2). Triple-buffered LDS,
// depth-2 prefetch, counted vmcnt (never 0 mid-loop) + raw s_barrier.
// Block order: XCD-chunked, bx OUTER / by INNER within a chunk so 4 concurrent
// blocks share one B-panel and each XCD fetches each B-panel once (L2-sized
// working set). Requires M/128 == 32 and grid == nbx*32.
// NORM: fused per-head RMSNorm on Q (cols<1024, *SCALE*LOG2E) / K (1024..2047).
template <int BN, bool F32OUT, bool NORM>
__global__ __launch_bounds__(256) void gemm_bf16(const short* __restrict__ A,
                                                 const short* __restrict__ Bt,
                                                 void* __restrict__ Cv,
                                                 const float* __restrict__ qw,
                                                 const float* __restrict__ kw,
                                                 int M, int N, int K, int nbx) {
  constexpr int NFR = BN / 32;
  constexpr int BITERS = BN / 64;
  __shared__ __attribute__((aligned(16))) short As[3][4096];
  __shared__ __attribute__((aligned(16))) short Bs[3][BN * 32];
  const int tid = threadIdx.x;
  const int w = tid >> 6, l = tid & 63;
  const int g = l >> 4, c = l & 15;
  const int wm = w >> 1, wn = w & 1;
  // XCD-chunked, B-panel-outer order: i>>2 = bx, xcd*4+(i&3) = by
  const int xcd = blockIdx.x & 7;
  const int i = blockIdx.x >> 3;
  const int bx = i >> 2;
  const int by = xcd * 4 + (i & 3);
  const int m0 = by * 128, n0 = bx * BN;
  const char* Ab = (const char*)A;
  const char* Bb = (const char*)Bt;

  auto stage = [&](int k0, int buf) {
#pragma unroll
    for (int ii = 0; ii < 2; ++ii) {
      int ci = w * 128 + ii * 64 + l;
      int row = ci >> 2, c4 = ci & 3;
      gld16(Ab + ((size_t)(m0 + row) * K + k0) * 2 + ((c4 ^ gswz(row)) << 4),
            (char*)As[buf] + (w * 2048 + ii * 1024));
    }
#pragma unroll
    for (int ii = 0; ii < BITERS; ++ii) {
      int ci = w * (64 * BITERS) + ii * 64 + l;
      int row = ci >> 2, c4 = ci & 3;
      gld16(Bb + ((size_t)(n0 + row) * K + k0) * 2 + ((c4 ^ gswz(row)) << 4),
            (char*)Bs[buf] + (w * (1024 * BITERS) + ii * 1024));
    }
  };

  f32x4 acc[4][NFR];
#pragma unroll
  for (int mt = 0; mt < 4; ++mt)
#pragma unroll
    for (int nt = 0; nt < NFR; ++nt) {
      f32x4 z = {0.f, 0.f, 0.f, 0.f};
      acc[mt][nt] = z;
    }

  const int NT = K >> 5;
  stage(0, 0);
  stage(32, 1);
  if constexpr (BITERS == 2) asm volatile("s_waitcnt vmcnt(4)" ::: "memory");
  else                       asm volatile("s_waitcnt vmcnt(3)" ::: "memory");
  __builtin_amdgcn_s_barrier();
  __builtin_amdgcn_sched_barrier(0);

  int cbuf = 0;
  for (int t = 0; t < NT; ++t) {
    int tgt = cbuf + 2; if (tgt >= 3) tgt -= 3;
    if (t + 2 < NT) stage((t + 2) << 5, tgt);
    bf16x8 a[4], bf[NFR];
#pragma unroll
    for (int mt = 0; mt < 4; ++mt) {
      const int row = wm * 64 + mt * 16 + c;
      a[mt] = *(const bf16x8*)&As[cbuf][row * 32 + ((g ^ gswz(row)) << 3)];
    }
#pragma unroll
    for (int nt = 0; nt < NFR; ++nt) {
      const int row = wn * (BN / 2) + nt * 16 + c;
      bf[nt] = *(const bf16x8*)&Bs[cbuf][row * 32 + ((g ^ gswz(row)) << 3)];
    }
    __builtin_amdgcn_s_setprio(1);
#pragma unroll
    for (int mt = 0; mt < 4; ++mt)
#pragma unroll
      for (int nt = 0; nt < NFR; ++nt)
        acc[mt][nt] = __builtin_amdgcn_mfma_f32_16x16x32_bf16(a[mt], bf[nt], acc[mt][nt], 0, 0, 0);
    __builtin_amdgcn_s_setprio(0);
    if (t + 1 < NT) {
      if (t + 2 < NT) {
        if constexpr (BITERS == 2) asm volatile("s_waitcnt vmcnt(4)" ::: "memory");
        else                       asm volatile("s_waitcnt vmcnt(3)" ::: "memory");
      } else {
        asm volatile("s_waitcnt vmcnt(0)" ::: "memory");
      }
      __builtin_amdgcn_s_barrier();
      __builtin_amdgcn_sched_barrier(0);
    }
    cbuf = cbuf + 1; if (cbuf >= 3) cbuf -= 3;
  }

  if constexpr (NORM) {
    if (n0 < 2048) {
      const float* wgt = (n0 < 1024) ? qw : kw;
      const float scl = (n0 < 1024) ? SCALE * LOG2E : 1.f;
      float w4[NFR];
#pragma unroll
      for (int nt = 0; nt < NFR; ++nt) w4[nt] = wgt[nt * 16 + c] * scl;
#pragma unroll
      for (int mt = 0; mt < 4; ++mt)
#pragma unroll
        for (int r = 0; r < 4; ++r) {
          float s = 0.f;
#pragma unroll
          for (int nt = 0; nt < NFR; ++nt) s += acc[mt][nt][r] * acc[mt][nt][r];
          s += __shfl_xor(s, 1);
          s += __shfl_xor(s, 2);
          s += __shfl_xor(s, 4);
          s += __shfl_xor(s, 8);
          const float rstd = rsqrtf(s * (1.0f / 64.0f) + EPSV);
#pragma unroll
          for (int nt = 0; nt < NFR; ++nt) acc[mt][nt][r] *= rstd * w4[nt];
        }
    }
  }

  if constexpr (F32OUT) {
    float* C = (float*)Cv;
#pragma unroll
    for (int mt = 0; mt < 4; ++mt)
#pragma unroll
      for (int nt = 0; nt < NFR; ++nt)
#pragma unroll
        for (int r = 0; r < 4; ++r)
          C[(size_t)(m0 + wm * 64 + mt * 16 + 4 * g + r) * N + n0 + wn * (BN / 2) + nt * 16 + c] =
              acc[mt][nt][r];
  } else {
    short* C = (short*)Cv;
#pragma unroll
    for (int mt = 0; mt < 4; ++mt)
#pragma unroll
      for (int nt = 0; nt < NFR; ++nt)
#pragma unroll
        for (int r = 0; r < 4; ++r)
          C[(size_t)(m0 + wm * 64 + mt * 16 + 4 * g + r) * N + n0 + wn * (BN / 2) + nt * 16 + c] =
              f2b(acc[mt][nt][r]);
  }
}

// ---------------- V transpose via LDS (coalesced both sides) ----------------
__global__ __launch_bounds__(256) void vt_kernel(const short* __restrict__ QKV,
                                                 short* __restrict__ VT) {
  __shared__ short tile[64][66];
  const int t0 = blockIdx.x * 64;
  const int h = blockIdx.y, b = blockIdx.z;
  const int tid = threadIdx.x;
  const int r = tid >> 3, c8 = (tid & 7) * 8;
#pragma unroll
  for (int p = 0; p < 2; ++p) {
    int row = r + p * 32;
    bf16x8 v = *(const bf16x8*)&QKV[(size_t)(b * T_SEQ + t0 + row) * 3072 + 2048 + h * 64 + c8];
#pragma unroll
    for (int j = 0; j < 8; ++j) tile[row][c8 + j] = v[j];
  }
  __syncthreads();
#pragma unroll
  for (int p = 0; p < 2; ++p) {
    int d = r + p * 32;
    short o[8];
#pragma unroll
    for (int j = 0; j < 8; ++j) o[j] = tile[c8 + j][d];
    *(bf16x8*)&VT[((size_t)(b * NHEAD + h) * 64 + d) * T_SEQ + t0 + c8] = *(bf16x8*)o;
  }
}

// ---------------- MFMA flash attention: 8-wave QBLK=128, counted-vmcnt ------
// 512 blocks (2/CU grid-limited, LDS 64 KB), block = (b,h,128 q rows). Pair map:
// CU's two residents get Q16 and 15-Q16 (34 k-iters total, same bh -> L2 reuse).
// Triple-buffered K/V, depth-2 prefetch, per-iter vmcnt(2) + one raw s_barrier.
// Fixed-max softmax: QK acc init = -SMAX, P = exp2(s); lsum via ones-MFMA.
__global__ __launch_bounds__(512, 4) void attn_fwd(const short* __restrict__ QKV,
                                                   const short* __restrict__ VT,
                                                   const float* __restrict__ gate,
                                                   short* __restrict__ Ob) {
  __shared__ __attribute__((aligned(16))) short pool[32768];  // 64 KB
  // shorts: [0,8192) Q 128x64 (dead after qf -> 8x 1K-short P slices);
  // [8192+buf*4096) K bufs (buf<3); [20480+buf*4096) V bufs.

  const int bid = blockIdx.x;
  const int xcd = bid & 7, s = bid >> 3;  // s 0..63
  const int t8 = (s >> 2) & 7;
  const int Q16 = (s < 32) ? 15 - t8 : t8;  // pair-balanced: s & s+32 sum to 34 iters
  const int bh = xcd * 4 + (s & 3);
  const int h = bh & 15, b = bh >> 4;
  const int q0 = Q16 * 128;
  const int nkt = 2 * Q16 + 2;
  const int tid = threadIdx.x;
  const int w = tid >> 6, l = tid & 63;
  const int g = l >> 4, c = l & 15;

  const char* qkb = (const char*)QKV;
  const char* kbase = qkb + ((size_t)(b * T_SEQ) * 3072 + 1024 + h * 64) * 2;
  const char* vtb = (const char*)VT + ((size_t)(b * NHEAD + h) * 64) * T_SEQ * 2;
  const float gh = gate[h];

  // prologue: Q (2 loads/lane), tiles 0 and 1 (2 loads/lane each; nkt >= 2 always)
  stage_sw(pool, qkb + ((size_t)(b * T_SEQ + q0) * 3072 + h * 64) * 2, 3072 * 2, w, l);
  stage_sw8(pool + 8192, kbase, 3072 * 2, w, l);
  stage_sw8(pool + 20480, vtb, T_SEQ * 2, w, l);
  stage_sw8(pool + 8192 + 4096, kbase + (size_t)64 * 3072 * 2, 3072 * 2, w, l);
  stage_sw8(pool + 20480 + 4096, vtb + (size_t)64 * 2, T_SEQ * 2, w, l);
  asm volatile("s_waitcnt vmcnt(4)" ::: "memory");  // Q landed; tiles 0,1 in flight
  __builtin_amdgcn_sched_barrier(0);

  // qf: wave w staged exactly rows 16w..16w+15 -> own-wave data, no barrier
  bf16x8 qf[2];
  {
    const int row = w * 16 + c;  // 0..127
#pragma unroll
    for (int ks = 0; ks < 2; ++ks)
      qf[ks] = *(const bf16x8*)&pool[row * 64 + ((ks * 32 + g * 8) ^ ((row & 7) << 3))];
  }
  short* ps = pool + (w << 10);  // per-wave P slice aliases this wave's Q rows

  bf16x8 onesf;
#pragma unroll
  for (int j = 0; j < 8; ++j) onesf[j] = (short)0x3F80;  // bf16 1.0

  f32x4 oacc[4];
#pragma unroll
  for (int dt = 0; dt < 4; ++dt) {
    f32x4 z = {0.f, 0.f, 0.f, 0.f};
    oacc[dt] = z;
  }
  f32x4 oacc4 = {0.f, 0.f, 0.f, 0.f};  // lsum accumulator (ones-MFMA)
  int cur = 0;

  for (int kt = 0; kt < nkt; ++kt) {
    // tile kt landed (leave tile kt+1's 2 loads in flight); sync; then prefetch kt+2
    if (kt + 1 < nkt) asm volatile("s_waitcnt vmcnt(2)" ::: "memory");
    else              asm volatile("s_waitcnt vmcnt(0)" ::: "memory");
    __builtin_amdgcn_s_barrier();
    __builtin_amdgcn_sched_barrier(0);
    if (kt + 2 < nkt) {
      int tgt = cur + 2; if (tgt >= 3) tgt -= 3;
      stage_sw8(pool + 8192 + (tgt << 12), kbase + (size_t)(kt + 2) * 64 * 3072 * 2, 3072 * 2, w, l);
      stage_sw8(pool + 20480 + (tgt << 12), vtb + (size_t)(kt + 2) * 64 * 2, T_SEQ * 2, w, l);
    }
    const short* Ks = pool + 8192 + (cur << 12);
    const short* Vs = pool + 20480 + (cur << 12);
    const int dq = q0 + w * 16 - kt * 64;  // wave-relative diagonal offset
    if (dq > -16) {  // wave has at least one unmasked (q,k) in this tile
      f32x4 sacc[4];
#pragma unroll
      for (int mt = 0; mt < 4; ++mt) {
        f32x4 z = {-SMAX, -SMAX, -SMAX, -SMAX};  // fixed-max subtract, free
        sacc[mt] = z;
      }
      __builtin_amdgcn_s_setprio(1);
#pragma unroll
      for (int mt = 0; mt < 4; ++mt) {
        const int row = mt * 16 + c;
#pragma unroll
        for (int ks = 0; ks < 2; ++ks) {
          bf16x8 kf = *(const bf16x8*)&Ks[row * 64 + ((ks * 32 + g * 8) ^ ((row & 7) << 3))];
          sacc[mt] = __builtin_amdgcn_mfma_f32_16x16x32_bf16(kf, qf[ks], sacc[mt], 0, 0, 0);
        }
      }
      __builtin_amdgcn_s_setprio(0);
      // hoist V fragment reads (overlap with softmax VALU)
      bf16x8 vf[4][2];
#pragma unroll
      for (int dt = 0; dt < 4; ++dt) {
        const int row = dt * 16 + c;
#pragma unroll
        for (int ks = 0; ks < 2; ++ks)
          vf[dt][ks] = *(const bf16x8*)&Vs[row * 64 + ((ks * 32 + g * 8) ^ ((row & 7) << 3))];
      }
      if (dq < 63) {  // diagonal tile for this wave: mask k > q
#pragma unroll
        for (int mt = 0; mt < 4; ++mt)
#pragma unroll
          for (int r = 0; r < 4; ++r)
            if (mt * 16 + 4 * g + r > dq + c) sacc[mt][r] = -1e30f;
      }
      // P = exp2(s) straight off MFMA output; pack and stash in ps
#pragma unroll
      for (int mt = 0; mt < 4; ++mt) {
        float p0 = exp2f(sacc[mt][0]);
        float p1 = exp2f(sacc[mt][1]);
        float p2 = exp2f(sacc[mt][2]);
        float p3 = exp2f(sacc[mt][3]);
        uint2 pk;
        pk.x = cvt_pk_bf16(p0, p1);
        pk.y = cvt_pk_bf16(p2, p3);
        *(uint2*)&ps[(c << 6) + ((mt * 16 + 4 * g) ^ ((c & 7) << 3))] = pk;
      }
      bf16x8 pb[2];
#pragma unroll
      for (int ks = 0; ks < 2; ++ks)
        pb[ks] = *(const bf16x8*)&ps[(c << 6) + ((ks * 32 + g * 8) ^ ((c & 7) << 3))];
      __builtin_amdgcn_s_setprio(1);
#pragma unroll
      for (int dt = 0; dt < 4; ++dt)
#pragma unroll
        for (int ks = 0; ks < 2; ++ks)
          oacc[dt] = __builtin_amdgcn_mfma_f32_16x16x32_bf16(vf[dt][ks], pb[ks], oacc[dt], 0, 0, 0);
      // lsum: row-sum of P via ones A-operand (matrix pipe, replaces VALU adds)
      oacc4 = __builtin_amdgcn_mfma_f32_16x16x32_bf16(onesf, pb[0], oacc4, 0, 0, 0);
      oacc4 = __builtin_amdgcn_mfma_f32_16x16x32_bf16(onesf, pb[1], oacc4, 0, 0, 0);
      __builtin_amdgcn_s_setprio(0);
    }
    cur = (cur + 1 == 3) ? 0 : cur + 1;
  }
  // epilogue: lsum from ones-MFMA (all 4 regs identical), gate/l, value residual
  const float gl = gh / oacc4[0];
  const int qrow = q0 + w * 16 + c;
  const short* Vr = QKV + (size_t)(b * T_SEQ + qrow) * 3072 + 2048 + h * 64;
  short* Oro = Ob + (size_t)(b * T_SEQ + qrow) * 1024 + h * 64;
#pragma unroll
  for (int dt = 0; dt < 4; ++dt) {
    const int d0 = dt * 16 + 4 * g;
    short4 vres = *(const short4*)&Vr[d0];
    short4 o;
    o.x = f2b(oacc[dt][0] * gl + b2f(vres.x));
    o.y = f2b(oacc[dt][1] * gl + b2f(vres.y));
    o.z = f2b(oacc[dt][2] * gl + b2f(vres.z));
    o.w = f2b(oacc[dt][3] * gl + b2f(vres.w));
    *(short4*)&Oro[d0] = o;
  }
}

extern "C" void kernel_launch(void* const* d_in, const int* in_sizes, int n_in,
                              void* d_out, int out_size, void* d_ws, size_t ws_size,
                              hipStream_t stream) {
  const float* x  = (const float*)d_in[0];
  const float* Wq = (const float*)d_in[2];
  const float* Wk = (const float*)d_in[3];
  const float* Wv = (const float*)d_in[4];
  const float* Wo = (const float*)d_in[5];
  const float* qw = (const float*)d_in[6];
  const float* kw = (const float*)d_in[7];
  const float* gate = (const float*)d_in[8];
  float* out = (float*)d_out;

  char* ws = (char*)d_ws;
  short* xb  = (short*)ws;                        // 8 MB
  short* WT  = (short*)(ws + ((size_t)8 << 20));  // 8 MB  [4096][1024]: WqT,WkT,WvT,WoT
  short* QKV = (short*)(ws + ((size_t)16 << 20)); // 24 MB [4096][3072]
  short* VTb = (short*)(ws + ((size_t)40 << 20)); // 8 MB  [b,h,64,2048]
  short* Obf = (short*)(ws + ((size_t)48 << 20)); // 8 MB  [4096][1024]

  const int M = BATCH * T_SEQ;  // 4096

  prep<<<3072, 256, 0, stream>>>(x, Wq, Wk, Wv, Wo, xb, WT);
  gemm_bf16<128, false, true><<<768, 256, 0, stream>>>(xb, WT, QKV, qw, kw, M, 3072, CDIM, 24);
  vt_kernel<<<dim3(32, 16, 2), 256, 0, stream>>>(QKV, VTb);
  attn_fwd<<<512, 512, 0, stream>>>(QKV, VTb, gate, Obf);
  gemm_bf16<64, true, false><<<512, 256, 0, stream>>>(Obf, WT + (size_t)3072 * 1024, out,
                                                      nullptr, nullptr, M, CDIM, CDIM, 16);
}

// Round 14
// 109.637 us; speedup vs baseline: 1.0388x; 1.0133x over previous
//
#include <hip/hip_runtime.h>

#define T_SEQ 2048
#define CDIM 1024
#define NHEAD 16
#define HDIM 64
#define BATCH 2
#define EPSV 1e-5f
#define SCALE 0.125f
#define LOG2E 1.44269504088896f
#define SMAX 16.0f  // fixed softmax max: scores bounded by 64*SCALE*LOG2E=11.54 < 16

typedef __attribute__((ext_vector_type(8))) short bf16x8;
typedef __attribute__((ext_vector_type(4))) float f32x4;

__device__ __forceinline__ float b2f(short s) {
  unsigned u = ((unsigned)(unsigned short)s) << 16;
  return __builtin_bit_cast(float, u);
}
__device__ __forceinline__ short f2b(float f) {
  unsigned u = __builtin_bit_cast(unsigned, f);
  unsigned r = (u + 0x7fffu + ((u >> 16) & 1u)) >> 16;
  return (short)r;
}
__device__ __forceinline__ unsigned cvt_pk_bf16(float a, float b) {
  unsigned r;
  asm("v_cvt_pk_bf16_f32 %0, %1, %2" : "=v"(r) : "v"(a), "v"(b));
  return r;
}

__device__ __forceinline__ void gld16(const void* g, void* l) {
  __builtin_amdgcn_global_load_lds((const __attribute__((address_space(1))) unsigned*)g,
                                   (__attribute__((address_space(3))) unsigned*)l, 16, 0, 0);
}

// GEMM tile swizzle.
__device__ __forceinline__ int gswz(int row) { return ((row >> 1) ^ (row >> 3)) & 3; }

// Stage rows of 128 B global->LDS, linear LDS dest, pre-swizzled global source:
// byte-in-row ^= (row&7)<<4.  stage_sw: 2 KB per wave (wave w -> rows 16w..16w+15).
__device__ __forceinline__ void stage_sw(short* lds, const char* gbase, int gstride,
                                         int w, int l) {
#pragma unroll
  for (int i = 0; i < 2; ++i) {
    int chunk = w * 2048 + i * 1024 + l * 16;
    int row = chunk >> 7;
    int bir = chunk & 127;
    const char* src = gbase + (size_t)row * gstride + (bir ^ ((row & 7) << 4));
    gld16(src, (char*)lds + chunk);
  }
}
// 1 KB per wave (8 waves cover a 64-row tile; wave w -> rows 8w..8w+7).
__device__ __forceinline__ void stage_sw8(short* lds, const char* gbase, int gstride,
                                          int w, int l) {
  int chunk = w * 1024 + l * 16;
  int row = chunk >> 7;
  int bir = chunk & 127;
  const char* src = gbase + (size_t)row * gstride + (bir ^ ((row & 7) << 4));
  gld16(src, (char*)lds + chunk);
}

// ---------------- prep: x fp32->bf16 (blocks 0..2047) + W transpose (2048..3071) ----
__global__ __launch_bounds__(256) void prep(const float* __restrict__ x,
                                            const float* __restrict__ Wq,
                                            const float* __restrict__ Wk,
                                            const float* __restrict__ Wv,
                                            const float* __restrict__ Wo,
                                            short* __restrict__ xb,
                                            short* __restrict__ WT) {
  __shared__ float tile[64][65];
  const int bid = blockIdx.x;
  if (bid < 2048) {
    size_t i = ((size_t)bid * 256 + threadIdx.x) * 8;
    float4 a = *(const float4*)&x[i];
    float4 b = *(const float4*)&x[i + 4];
    short4 lo, hi;
    lo.x = f2b(a.x); lo.y = f2b(a.y); lo.z = f2b(a.z); lo.w = f2b(a.w);
    hi.x = f2b(b.x); hi.y = f2b(b.y); hi.z = f2b(b.z); hi.w = f2b(b.w);
    *(short4*)&xb[i] = lo;
    *(short4*)&xb[i + 4] = hi;
    return;
  }
  const int t = bid - 2048;
  const int z = t >> 8, rem = t & 255;
  const float* W = (z == 0) ? Wq : (z == 1) ? Wk : (z == 2) ? Wv : Wo;
  const int r0 = (rem >> 4) * 64, c0 = (rem & 15) * 64;
  const int tr = threadIdx.x >> 4, tc4 = (threadIdx.x & 15) * 4;
#pragma unroll
  for (int i = 0; i < 4; ++i) {
    float4 v = *(const float4*)&W[(size_t)(r0 + tr + i * 16) * 1024 + c0 + tc4];
    tile[tr + i * 16][tc4 + 0] = v.x;
    tile[tr + i * 16][tc4 + 1] = v.y;
    tile[tr + i * 16][tc4 + 2] = v.z;
    tile[tr + i * 16][tc4 + 3] = v.w;
  }
  __syncthreads();
#pragma unroll
  for (int i = 0; i < 4; ++i) {
    int n = tr + i * 16;
    short4 o;
    o.x = f2b(tile[tc4 + 0][n]);
    o.y = f2b(tile[tc4 + 1][n]);
    o.z = f2b(tile[tc4 + 2][n]);
    o.w = f2b(tile[tc4 + 3][n]);
    *(short4*)&WT[((size_t)(z * 1024) + c0 + n) * 1024 + r0 + tc4] = o;
  }
}

// ---------------- bf16 MFMA GEMM: C[M,N] = A[M,K] @ Bt[N,K]^T ----------------
// BM=128, BN templated, BK=32, 256 threads (4 waves 2x2). Triple-buffered LDS,
// depth-2 prefetch, counted vmcnt + raw s_barrier. B-panel-outer block order.
template <int BN, bool F32OUT, bool NORM>
__global__ __launch_bounds__(256) void gemm_bf16(const short* __restrict__ A,
                                                 const short* __restrict__ Bt,
                                                 void* __restrict__ Cv,
                                                 const float* __restrict__ qw,
                                                 const float* __restrict__ kw,
                                                 int M, int N, int K, int nbx) {
  constexpr int NFR = BN / 32;
  constexpr int BITERS = BN / 64;
  __shared__ __attribute__((aligned(16))) short As[3][4096];
  __shared__ __attribute__((aligned(16))) short Bs[3][BN * 32];
  const int tid = threadIdx.x;
  const int w = tid >> 6, l = tid & 63;
  const int g = l >> 4, c = l & 15;
  const int wm = w >> 1, wn = w & 1;
  const int xcd = blockIdx.x & 7;
  const int i = blockIdx.x >> 3;
  const int bx = i >> 2;
  const int by = xcd * 4 + (i & 3);
  const int m0 = by * 128, n0 = bx * BN;
  const char* Ab = (const char*)A;
  const char* Bb = (const char*)Bt;

  auto stage = [&](int k0, int buf) {
#pragma unroll
    for (int ii = 0; ii < 2; ++ii) {
      int ci = w * 128 + ii * 64 + l;
      int row = ci >> 2, c4 = ci & 3;
      gld16(Ab + ((size_t)(m0 + row) * K + k0) * 2 + ((c4 ^ gswz(row)) << 4),
            (char*)As[buf] + (w * 2048 + ii * 1024));
    }
#pragma unroll
    for (int ii = 0; ii < BITERS; ++ii) {
      int ci = w * (64 * BITERS) + ii * 64 + l;
      int row = ci >> 2, c4 = ci & 3;
      gld16(Bb + ((size_t)(n0 + row) * K + k0) * 2 + ((c4 ^ gswz(row)) << 4),
            (char*)Bs[buf] + (w * (1024 * BITERS) + ii * 1024));
    }
  };

  f32x4 acc[4][NFR];
#pragma unroll
  for (int mt = 0; mt < 4; ++mt)
#pragma unroll
    for (int nt = 0; nt < NFR; ++nt) {
      f32x4 z = {0.f, 0.f, 0.f, 0.f};
      acc[mt][nt] = z;
    }

  const int NT = K >> 5;
  stage(0, 0);
  stage(32, 1);
  if constexpr (BITERS == 2) asm volatile("s_waitcnt vmcnt(4)" ::: "memory");
  else                       asm volatile("s_waitcnt vmcnt(3)" ::: "memory");
  __builtin_amdgcn_s_barrier();
  __builtin_amdgcn_sched_barrier(0);

  int cbuf = 0;
  for (int t = 0; t < NT; ++t) {
    int tgt = cbuf + 2; if (tgt >= 3) tgt -= 3;
    if (t + 2 < NT) stage((t + 2) << 5, tgt);
    bf16x8 a[4], bf[NFR];
#pragma unroll
    for (int mt = 0; mt < 4; ++mt) {
      const int row = wm * 64 + mt * 16 + c;
      a[mt] = *(const bf16x8*)&As[cbuf][row * 32 + ((g ^ gswz(row)) << 3)];
    }
#pragma unroll
    for (int nt = 0; nt < NFR; ++nt) {
      const int row = wn * (BN / 2) + nt * 16 + c;
      bf[nt] = *(const bf16x8*)&Bs[cbuf][row * 32 + ((g ^ gswz(row)) << 3)];
    }
    __builtin_amdgcn_s_setprio(1);
#pragma unroll
    for (int mt = 0; mt < 4; ++mt)
#pragma unroll
      for (int nt = 0; nt < NFR; ++nt)
        acc[mt][nt] = __builtin_amdgcn_mfma_f32_16x16x32_bf16(a[mt], bf[nt], acc[mt][nt], 0, 0, 0);
    __builtin_amdgcn_s_setprio(0);
    if (t + 1 < NT) {
      if (t + 2 < NT) {
        if constexpr (BITERS == 2) asm volatile("s_waitcnt vmcnt(4)" ::: "memory");
        else                       asm volatile("s_waitcnt vmcnt(3)" ::: "memory");
      } else {
        asm volatile("s_waitcnt vmcnt(0)" ::: "memory");
      }
      __builtin_amdgcn_s_barrier();
      __builtin_amdgcn_sched_barrier(0);
    }
    cbuf = cbuf + 1; if (cbuf >= 3) cbuf -= 3;
  }

  if constexpr (NORM) {
    if (n0 < 2048) {
      const float* wgt = (n0 < 1024) ? qw : kw;
      const float scl = (n0 < 1024) ? SCALE * LOG2E : 1.f;
      float w4[NFR];
#pragma unroll
      for (int nt = 0; nt < NFR; ++nt) w4[nt] = wgt[nt * 16 + c] * scl;
#pragma unroll
      for (int mt = 0; mt < 4; ++mt)
#pragma unroll
        for (int r = 0; r < 4; ++r) {
          float s = 0.f;
#pragma unroll
          for (int nt = 0; nt < NFR; ++nt) s += acc[mt][nt][r] * acc[mt][nt][r];
          s += __shfl_xor(s, 1);
          s += __shfl_xor(s, 2);
          s += __shfl_xor(s, 4);
          s += __shfl_xor(s, 8);
          const float rstd = rsqrtf(s * (1.0f / 64.0f) + EPSV);
#pragma unroll
          for (int nt = 0; nt < NFR; ++nt) acc[mt][nt][r] *= rstd * w4[nt];
        }
    }
  }

  if constexpr (F32OUT) {
    float* C = (float*)Cv;
#pragma unroll
    for (int mt = 0; mt < 4; ++mt)
#pragma unroll
      for (int nt = 0; nt < NFR; ++nt)
#pragma unroll
        for (int r = 0; r < 4; ++r)
          C[(size_t)(m0 + wm * 64 + mt * 16 + 4 * g + r) * N + n0 + wn * (BN / 2) + nt * 16 + c] =
              acc[mt][nt][r];
  } else {
    short* C = (short*)Cv;
#pragma unroll
    for (int mt = 0; mt < 4; ++mt)
#pragma unroll
      for (int nt = 0; nt < NFR; ++nt)
#pragma unroll
        for (int r = 0; r < 4; ++r)
          C[(size_t)(m0 + wm * 64 + mt * 16 + 4 * g + r) * N + n0 + wn * (BN / 2) + nt * 16 + c] =
              f2b(acc[mt][nt][r]);
  }
}

// ---------------- V transpose via LDS (coalesced both sides) ----------------
__global__ __launch_bounds__(256) void vt_kernel(const short* __restrict__ QKV,
                                                 short* __restrict__ VT) {
  __shared__ short tile[64][66];
  const int t0 = blockIdx.x * 64;
  const int h = blockIdx.y, b = blockIdx.z;
  const int tid = threadIdx.x;
  const int r = tid >> 3, c8 = (tid & 7) * 8;
#pragma unroll
  for (int p = 0; p < 2; ++p) {
    int row = r + p * 32;
    bf16x8 v = *(const bf16x8*)&QKV[(size_t)(b * T_SEQ + t0 + row) * 3072 + 2048 + h * 64 + c8];
#pragma unroll
    for (int j = 0; j < 8; ++j) tile[row][c8 + j] = v[j];
  }
  __syncthreads();
#pragma unroll
  for (int p = 0; p < 2; ++p) {
    int d = r + p * 32;
    short o[8];
#pragma unroll
    for (int j = 0; j < 8; ++j) o[j] = tile[c8 + j][d];
    *(bf16x8*)&VT[((size_t)(b * NHEAD + h) * 64 + d) * T_SEQ + t0 + c8] = *(bf16x8*)o;
  }
}

// ---------------- MFMA flash attention: 8-wave QBLK=128, static-unroll-3 -----
// 512 blocks (2/CU, LDS 64 KB). Triple-buffered K/V (8 KB tiles, 8 KB stride!),
// depth-2 prefetch, counted vmcnt(2) + one raw s_barrier per tile. Loop
// unrolled x3 so the buffer index is COMPILE-TIME: all swizzled LDS accesses
// become (loop-invariant per-lane addr reg) + ds offset:imm; swizzle
// decomposition (no cross-field carries):
//   byteoff = c*128 + ((g^(c&3))<<4) + ((ks^((c>>2)&1))<<6) + mt*2048 + BUF*8192.
// Fixed-max softmax: QK acc init = -SMAX, P = exp2(s); lsum via ones-MFMA.
__global__ __launch_bounds__(512, 4) void attn_fwd(const short* __restrict__ QKV,
                                                   const short* __restrict__ VT,
                                                   const float* __restrict__ gate,
                                                   short* __restrict__ Ob) {
  __shared__ __attribute__((aligned(16))) short pool[32768];  // 64 KB
  // shorts: [0,8192) Q 128x64 (dead after qf -> 8x 1K-short P slices);
  // [8192 + buf*4096) K bufs (buf<3, 4096 shorts each);
  // [20480 + buf*4096) V bufs.

  const int bid = blockIdx.x;
  const int xcd = bid & 7, s = bid >> 3;  // s 0..63
  const int t8 = (s >> 2) & 7;
  const int Q16 = (s < 32) ? 15 - t8 : t8;  // pair-balanced: s & s+32 sum to 34 iters
  const int bh = xcd * 4 + (s & 3);
  const int h = bh & 15, b = bh >> 4;
  const int q0 = Q16 * 128;
  const int nkt = 2 * Q16 + 2;
  const int tid = threadIdx.x;
  const int w = tid >> 6, l = tid & 63;
  const int g = l >> 4, c = l & 15;

  const char* qkb = (const char*)QKV;
  const char* kbase = qkb + ((size_t)(b * T_SEQ) * 3072 + 1024 + h * 64) * 2;
  const char* vtb = (const char*)VT + ((size_t)(b * NHEAD + h) * 64) * T_SEQ * 2;
  const float gh = gate[h];

  // prologue: Q (2 loads/lane), tiles 0 and 1 (2 loads/lane each; nkt >= 2 always)
  stage_sw(pool, qkb + ((size_t)(b * T_SEQ + q0) * 3072 + h * 64) * 2, 3072 * 2, w, l);
  stage_sw8(pool + 8192, kbase, 3072 * 2, w, l);
  stage_sw8(pool + 20480, vtb, T_SEQ * 2, w, l);
  stage_sw8(pool + 8192 + 4096, kbase + (size_t)64 * 3072 * 2, 3072 * 2, w, l);
  stage_sw8(pool + 20480 + 4096, vtb + (size_t)64 * 2, T_SEQ * 2, w, l);
  asm volatile("s_waitcnt vmcnt(4)" ::: "memory");  // Q landed; tiles 0,1 in flight
  __builtin_amdgcn_sched_barrier(0);

  // qf: wave w staged exactly rows 16w..16w+15 -> own-wave data, no barrier
  bf16x8 qf[2];
  {
    const int row = w * 16 + c;  // 0..127
#pragma unroll
    for (int ks = 0; ks < 2; ++ks)
      qf[ks] = *(const bf16x8*)&pool[row * 64 + ((ks * 32 + g * 8) ^ ((row & 7) << 3))];
  }

  // --- loop-invariant per-lane LDS byte offsets (swizzle pre-decomposed) ---
  const char* poolb = (const char*)pool;
  const int bc = (c >> 2) & 1;
  const int swz_g = (g ^ (c & 3)) << 4;
  const int kvoff[2] = {c * 128 + swz_g + (bc << 6),          // ks=0
                        c * 128 + swz_g + ((1 ^ bc) << 6)};   // ks=1
  const int pboff[2] = {w * 2048 + kvoff[0], w * 2048 + kvoff[1]};
  const int cc = (c >> 1) & 3;
  const int pinv = w * 2048 + c * 128 + ((g & 1) << 3) + ((((g >> 1) ^ c) & 1) << 4);
  int p_off[4];
#pragma unroll
  for (int mt = 0; mt < 4; ++mt) p_off[mt] = pinv + ((mt ^ cc) << 5);

  bf16x8 onesf;
#pragma unroll
  for (int j = 0; j < 8; ++j) onesf[j] = (short)0x3F80;  // bf16 1.0

  f32x4 oacc[4];
#pragma unroll
  for (int dt = 0; dt < 4; ++dt) {
    f32x4 z = {0.f, 0.f, 0.f, 0.f};
    oacc[dt] = z;
  }
  f32x4 oacc4 = {0.f, 0.f, 0.f, 0.f};  // lsum accumulator (ones-MFMA)

// one k-tile body; BUF_ is compile-time (tile kt uses buffer kt%3).
// K buf BUF at byte 16384 + BUF*8192; V buf at byte 40960 + BUF*8192.
#define ATTN_BODY(BUF_, KT_)                                                              \
  {                                                                                       \
    constexpr int BUF = (BUF_);                                                           \
    const int kt = (KT_);                                                                 \
    if (kt + 1 < nkt) asm volatile("s_waitcnt vmcnt(2)" ::: "memory");                    \
    else              asm volatile("s_waitcnt vmcnt(0)" ::: "memory");                    \
    __builtin_amdgcn_s_barrier();                                                         \
    __builtin_amdgcn_sched_barrier(0);                                                    \
    if (kt + 2 < nkt) {                                                                   \
      constexpr int TGT = (BUF + 2) % 3;                                                  \
      stage_sw8(pool + 8192 + TGT * 4096, kbase + (size_t)(kt + 2) * 64 * 3072 * 2,       \
                3072 * 2, w, l);                                                          \
      stage_sw8(pool + 20480 + TGT * 4096, vtb + (size_t)(kt + 2) * 64 * 2,               \
                T_SEQ * 2, w, l);                                                         \
    }                                                                                     \
    const int dq = q0 + w * 16 - kt * 64;                                                 \
    if (dq > -16) {                                                                       \
      f32x4 sacc[4];                                                                      \
      _Pragma("unroll") for (int mt = 0; mt < 4; ++mt) {                                  \
        f32x4 z = {-SMAX, -SMAX, -SMAX, -SMAX};                                           \
        sacc[mt] = z;                                                                     \
      }                                                                                   \
      __builtin_amdgcn_s_setprio(1);                                                      \
      _Pragma("unroll") for (int mt = 0; mt < 4; ++mt) {                                  \
        _Pragma("unroll") for (int ks = 0; ks < 2; ++ks) {                                \
          bf16x8 kf = *(const bf16x8*)(poolb + 16384 + BUF * 8192 + mt * 2048 +           \
                                       kvoff[ks]);                                        \
          sacc[mt] = __builtin_amdgcn_mfma_f32_16x16x32_bf16(kf, qf[ks], sacc[mt],        \
                                                             0, 0, 0);                    \
        }                                                                                 \
      }                                                                                   \
      __builtin_amdgcn_s_setprio(0);                                                      \
      bf16x8 vf[4][2];                                                                    \
      _Pragma("unroll") for (int dt = 0; dt < 4; ++dt)                                    \
        _Pragma("unroll") for (int ks = 0; ks < 2; ++ks)                                  \
          vf[dt][ks] = *(const bf16x8*)(poolb + 40960 + BUF * 8192 + dt * 2048 +          \
                                        kvoff[ks]);                                       \
      if (dq < 63) {                                                                      \
        _Pragma("unroll") for (int mt = 0; mt < 4; ++mt)                                  \
          _Pragma("unroll") for (int r = 0; r < 4; ++r)                                   \
            if (mt * 16 + 4 * g + r > dq + c) sacc[mt][r] = -1e30f;                       \
      }                                                                                   \
      _Pragma("unroll") for (int mt = 0; mt < 4; ++mt) {                                  \
        float p0 = exp2f(sacc[mt][0]);                                                    \
        float p1 = exp2f(sacc[mt][1]);                                                    \
        float p2 = exp2f(sacc[mt][2]);                                                    \
        float p3 = exp2f(sacc[mt][3]);                                                    \
        uint2 pk;                                                                         \
        pk.x = cvt_pk_bf16(p0, p1);                                                       \
        pk.y = cvt_pk_bf16(p2, p3);                                                       \
        *(uint2*)((char*)pool + p_off[mt]) = pk;                                          \
      }                                                                                   \
      bf16x8 pb[2];                                                                       \
      _Pragma("unroll") for (int ks = 0; ks < 2; ++ks)                                    \
        pb[ks] = *(const bf16x8*)(poolb + pboff[ks]);                                     \
      __builtin_amdgcn_s_setprio(1);                                                      \
      _Pragma("unroll") for (int dt = 0; dt < 4; ++dt)                                    \
        _Pragma("unroll") for (int ks = 0; ks < 2; ++ks)                                  \
          oacc[dt] = __builtin_amdgcn_mfma_f32_16x16x32_bf16(vf[dt][ks], pb[ks],          \
                                                             oacc[dt], 0, 0, 0);          \
      oacc4 = __builtin_amdgcn_mfma_f32_16x16x32_bf16(onesf, pb[0], oacc4, 0, 0, 0);      \
      oacc4 = __builtin_amdgcn_mfma_f32_16x16x32_bf16(onesf, pb[1], oacc4, 0, 0, 0);      \
      __builtin_amdgcn_s_setprio(0);                                                      \
    }                                                                                     \
  }

  int base = 0;
  for (; base + 3 <= nkt; base += 3) {
    ATTN_BODY(0, base);
    ATTN_BODY(1, base + 1);
    ATTN_BODY(2, base + 2);
  }
  if (base < nkt) ATTN_BODY(0, base);
  if (base + 1 < nkt) ATTN_BODY(1, base + 1);
#undef ATTN_BODY

  // epilogue: lsum from ones-MFMA (all 4 regs identical), gate/l, value residual
  const float gl = gh / oacc4[0];
  const int qrow = q0 + w * 16 + c;
  const short* Vr = QKV + (size_t)(b * T_SEQ + qrow) * 3072 + 2048 + h * 64;
  short* Oro = Ob + (size_t)(b * T_SEQ + qrow) * 1024 + h * 64;
#pragma unroll
  for (int dt = 0; dt < 4; ++dt) {
    const int d0 = dt * 16 + 4 * g;
    short4 vres = *(const short4*)&Vr[d0];
    short4 o;
    o.x = f2b(oacc[dt][0] * gl + b2f(vres.x));
    o.y = f2b(oacc[dt][1] * gl + b2f(vres.y));
    o.z = f2b(oacc[dt][2] * gl + b2f(vres.z));
    o.w = f2b(oacc[dt][3] * gl + b2f(vres.w));
    *(short4*)&Oro[d0] = o;
  }
}

extern "C" void kernel_launch(void* const* d_in, const int* in_sizes, int n_in,
                              void* d_out, int out_size, void* d_ws, size_t ws_size,
                              hipStream_t stream) {
  const float* x  = (const float*)d_in[0];
  const float* Wq = (const float*)d_in[2];
  const float* Wk = (const float*)d_in[3];
  const float* Wv = (const float*)d_in[4];
  const float* Wo = (const float*)d_in[5];
  const float* qw = (const float*)d_in[6];
  const float* kw = (const float*)d_in[7];
  const float* gate = (const float*)d_in[8];
  float* out = (float*)d_out;

  char* ws = (char*)d_ws;
  short* xb  = (short*)ws;                        // 8 MB
  short* WT  = (short*)(ws + ((size_t)8 << 20));  // 8 MB  [4096][1024]: WqT,WkT,WvT,WoT
  short* QKV = (short*)(ws + ((size_t)16 << 20)); // 24 MB [4096][3072]
  short* VTb = (short*)(ws + ((size_t)40 << 20)); // 8 MB  [b,h,64,2048]
  short* Obf = (short*)(ws + ((size_t)48 << 20)); // 8 MB  [4096][1024]

  const int M = BATCH * T_SEQ;  // 4096

  prep<<<3072, 256, 0, stream>>>(x, Wq, Wk, Wv, Wo, xb, WT);
  gemm_bf16<128, false, true><<<768, 256, 0, stream>>>(xb, WT, QKV, qw, kw, M, 3072, CDIM, 24);
  vt_kernel<<<dim3(32, 16, 2), 256, 0, stream>>>(QKV, VTb);
  attn_fwd<<<512, 512, 0, stream>>>(QKV, VTb, gate, Obf);
  gemm_bf16<64, true, false><<<512, 256, 0, stream>>>(Obf, WT + (size_t)3072 * 1024, out,
                                                      nullptr, nullptr, M, CDIM, CDIM, 16);
}